// Round 4
// baseline (617.137 us; speedup 1.0000x reference)
//
#include <hip/hip_runtime.h>
#include <math.h>
#include <stdint.h>

// ---------------- problem constants ----------------
#define T_TOK  8192
#define DMODEL 1024
#define DFF    4096
#define NEXP   8
#define MAXTILES 71      // sum ceil(cnt_e/128) <= 64 + (NEXP-1)

// ---------------- workspace layout (bytes) ----------------
static constexpr size_t OFF_COUNTS  = 0;
static constexpr size_t OFF_CURSOR  = 64;
static constexpr size_t OFF_OFFSETS = 128;
static constexpr size_t OFF_TILES   = 256;   // MAXTILES ints
static constexpr size_t OFF_NTILES  = 768;
static constexpr size_t OFF_EIDX    = 1024;
static constexpr size_t OFF_EW      = OFF_EIDX + (size_t)T_TOK * 4;
static constexpr size_t OFF_PERM    = OFF_EW   + (size_t)T_TOK * 4;
static constexpr size_t OFF_XB      = 131072;                                   // bf16 x  [T][D]
static constexpr size_t OFF_W1B     = OFF_XB  + (size_t)T_TOK * DMODEL * 2;     // bf16 w1^T [E][DFF][D]
static constexpr size_t OFF_W2B     = OFF_W1B + (size_t)NEXP * DFF * DMODEL * 2;// bf16 w2^T [E][D][DFF]
static constexpr size_t OFF_HB      = OFF_W2B + (size_t)NEXP * DMODEL * DFF * 2;// bf16 h  [T][DFF] grouped

typedef __attribute__((ext_vector_type(8))) short short8;
typedef __attribute__((ext_vector_type(4))) float floatx4;

__device__ __forceinline__ unsigned short f2bf(float f) {
    unsigned u = __builtin_bit_cast(unsigned, f);
    u += 0x7fffu + ((u >> 16) & 1u);   // round-to-nearest-even
    return (unsigned short)(u >> 16);
}

__device__ __forceinline__ void async16(const unsigned short* g, unsigned short* l) {
    __builtin_amdgcn_global_load_lds(
        (const __attribute__((address_space(1))) unsigned*)g,
        (__attribute__((address_space(3))) unsigned*)l, 16, 0, 0);
}

// tanh-form GELU via sigmoid: gelu(x) ~= x * sigmoid(2*sqrt(2/pi)*(x+0.044715x^3))
// max abs error vs exact-erf GELU ~3e-4, far below bf16 quantization of h.
__device__ __forceinline__ float gelu_fast(float v) {
    float u2 = v * (1.5957691216f + 0.0713548163f * v * v);
    return v / (1.0f + __expf(-u2));
}

// ---------------- small setup kernels ----------------
__global__ void zero_kernel(int* counts, int* cursor) {
    int t = threadIdx.x;
    if (t < NEXP) { counts[t] = 0; cursor[t] = 0; }
}

// src [E][K][N] fp32  ->  dst [E][N][K] bf16, 16B vectorized both sides
__global__ __launch_bounds__(256) void transpose_cvt_kernel(const float* __restrict__ src,
                                                            unsigned short* __restrict__ dst,
                                                            int K, int N) {
    int e  = blockIdx.z;
    int k0 = blockIdx.x * 64;
    int n0 = blockIdx.y * 64;
    const float* s = src + (size_t)e * K * N;
    unsigned short* d = dst + (size_t)e * K * N;
    __shared__ float tile[64][65];
    int tid = threadIdx.x;
    int lane16 = tid & 15, rowb = tid >> 4;   // 16 rows per pass
#pragma unroll
    for (int i = 0; i < 4; i++) {
        int row = i * 16 + rowb;
        float4 v = *(const float4*)(s + (size_t)(k0 + row) * N + n0 + lane16 * 4);
        tile[row][lane16 * 4 + 0] = v.x;
        tile[row][lane16 * 4 + 1] = v.y;
        tile[row][lane16 * 4 + 2] = v.z;
        tile[row][lane16 * 4 + 3] = v.w;
    }
    __syncthreads();
    int n = tid >> 2, kq = tid & 3;
#pragma unroll
    for (int h = 0; h < 2; h++) {
        int kk = (kq + h * 4) * 8;
        unsigned pk[4];
#pragma unroll
        for (int j = 0; j < 4; j++) {
            unsigned lo = f2bf(tile[kk + 2 * j][n]);
            unsigned hi = f2bf(tile[kk + 2 * j + 1][n]);
            pk[j] = lo | (hi << 16);
        }
        *(uint4*)(d + (size_t)(n0 + n) * K + k0 + kk) = *(uint4*)pk;
    }
}

// ---------------- router: logits via LDS-transposed gate_w, softmax, argmax,
// fused per-block expert histogram; also emits xb (bf16 x) ----------------
__global__ __launch_bounds__(256) void router_kernel(const float* __restrict__ x,
                                                     const float* __restrict__ gw,
                                                     int* __restrict__ eidx,
                                                     float* __restrict__ ew,
                                                     unsigned short* __restrict__ xb,
                                                     int* __restrict__ counts) {
    __shared__ float gwT[NEXP][DMODEL];   // 32 KiB, transposed gate_w
    __shared__ int lh[NEXP];
    int tid = threadIdx.x, lane = tid & 63, w = tid >> 6;
    if (tid < NEXP) lh[tid] = 0;
    {   // cooperative load gw [1024][8] -> gwT[e][d]; 4 d-rows per thread
        int d0 = tid * 4;
        const float* g = gw + (size_t)d0 * NEXP;
        float4 a0 = *(const float4*)(g +  0), b0 = *(const float4*)(g +  4);
        float4 a1 = *(const float4*)(g +  8), b1 = *(const float4*)(g + 12);
        float4 a2 = *(const float4*)(g + 16), b2 = *(const float4*)(g + 20);
        float4 a3 = *(const float4*)(g + 24), b3 = *(const float4*)(g + 28);
        *(float4*)&gwT[0][d0] = float4{a0.x, a1.x, a2.x, a3.x};
        *(float4*)&gwT[1][d0] = float4{a0.y, a1.y, a2.y, a3.y};
        *(float4*)&gwT[2][d0] = float4{a0.z, a1.z, a2.z, a3.z};
        *(float4*)&gwT[3][d0] = float4{a0.w, a1.w, a2.w, a3.w};
        *(float4*)&gwT[4][d0] = float4{b0.x, b1.x, b2.x, b3.x};
        *(float4*)&gwT[5][d0] = float4{b0.y, b1.y, b2.y, b3.y};
        *(float4*)&gwT[6][d0] = float4{b0.z, b1.z, b2.z, b3.z};
        *(float4*)&gwT[7][d0] = float4{b0.w, b1.w, b2.w, b3.w};
    }
    __syncthreads();

    int t = blockIdx.x * 4 + w;
    float acc[NEXP];
#pragma unroll
    for (int e = 0; e < NEXP; e++) acc[e] = 0.f;
    const float* xr = x + (size_t)t * DMODEL;
    unsigned short* xbr = xb + (size_t)t * DMODEL;
#pragma unroll
    for (int i = 0; i < 4; i++) {
        int dbase = i * 256 + lane * 4;
        float4 xv = *(const float4*)(xr + dbase);
        uint2 p;
        p.x = (unsigned)f2bf(xv.x) | ((unsigned)f2bf(xv.y) << 16);
        p.y = (unsigned)f2bf(xv.z) | ((unsigned)f2bf(xv.w) << 16);
        *(uint2*)(xbr + dbase) = p;
#pragma unroll
        for (int e = 0; e < NEXP; e++) {
            float4 g = *(const float4*)&gwT[e][dbase];   // ds_read_b128, conflict-free
            acc[e] += xv.x * g.x + xv.y * g.y + xv.z * g.z + xv.w * g.w;
        }
    }
#pragma unroll
    for (int e = 0; e < NEXP; e++) {
#pragma unroll
        for (int o = 32; o > 0; o >>= 1) acc[e] += __shfl_xor(acc[e], o, 64);
    }
    float m = acc[0]; int a = 0;
#pragma unroll
    for (int e = 1; e < NEXP; e++) { if (acc[e] > m) { m = acc[e]; a = e; } }
    float s = 0.f;
#pragma unroll
    for (int e = 0; e < NEXP; e++) s += expf(acc[e] - m);
    if (lane == 0) { eidx[t] = a; ew[t] = 1.0f / s; atomicAdd(&lh[a], 1); }
    __syncthreads();
    if (tid < NEXP && lh[tid]) atomicAdd(&counts[tid], lh[tid]);
}

// ---------------- grouping ----------------
__global__ void scan_kernel(const int* __restrict__ counts, int* __restrict__ offsets,
                            int* __restrict__ cursor, int* __restrict__ tiletab,
                            int* __restrict__ ntiles) {
    if (threadIdx.x == 0) {
        int s = 0, nt = 0;
        for (int e = 0; e < NEXP; e++) {
            offsets[e] = s; cursor[e] = s;
            int c = counts[e];
            int m = (c + 127) >> 7;
            for (int i = 0; i < m; i++) tiletab[nt++] = (e << 16) | i;
            s += c;
        }
        offsets[NEXP] = s;
        ntiles[0] = nt;
    }
}

__global__ void scatter_kernel(const int* __restrict__ eidx, int* __restrict__ cursor,
                               int* __restrict__ perm) {
    __shared__ int lh[NEXP];
    __shared__ int lbase[NEXP];
    int tid = threadIdx.x;
    if (tid < NEXP) lh[tid] = 0;
    __syncthreads();
    int t = blockIdx.x * 256 + tid;
    int e = eidx[t];
    int lpos = atomicAdd(&lh[e], 1);
    __syncthreads();
    if (tid < NEXP) lbase[tid] = atomicAdd(&cursor[tid], lh[tid]);
    __syncthreads();
    perm[lbase[e] + lpos] = t;
}

// ---------------- GEMM1: h = gelu(x[perm] @ w1 + b1), bf16 MFMA ----------------
__global__ __launch_bounds__(256, 4) void gemm1_kernel(
    const unsigned short* __restrict__ xb,
    const unsigned short* __restrict__ w1b,   // [E][DFF][DMODEL]
    const float* __restrict__ b1,             // [E][DFF]
    const int* __restrict__ counts,
    const int* __restrict__ offsets,
    const int* __restrict__ perm,
    const int* __restrict__ tiletab,
    const int* __restrict__ ntiles,
    unsigned short* __restrict__ hb)          // [T][DFF] grouped rows
{
    const int ti = blockIdx.y;
    if (ti >= ntiles[0]) return;
    const int tv = tiletab[ti];
    const int e = tv >> 16, mt = tv & 0xffff, nt = blockIdx.x;
    const int cnt = counts[e];
    const int off = offsets[e];
    const int tid = threadIdx.x, lane = tid & 63, wave = tid >> 6;
    const int wm = (wave >> 1) * 64, wn = (wave & 1) * 64;
    const int lm = lane & 15, quad = lane >> 4;

    __shared__ __attribute__((aligned(16))) unsigned short As[128 * 64];
    __shared__ __attribute__((aligned(16))) unsigned short Bs[128 * 64];

    const unsigned short* a_src[4];
    const unsigned short* b_src[4];
    const int cntLoc = cnt - mt * 128;
#pragma unroll
    for (int i = 0; i < 4; i++) {
        int c = i * 256 + tid;
        int row = c >> 3;
        int g = (c & 7) ^ (row & 7);          // XOR-swizzled 16B granule
        int r = (row < cntLoc) ? row : 0;
        int tok = perm[off + mt * 128 + r];
        a_src[i] = xb + (size_t)tok * DMODEL + g * 8;
        b_src[i] = w1b + ((size_t)e * DFF + nt * 128 + row) * DMODEL + g * 8;
    }

    floatx4 acc[4][4];
#pragma unroll
    for (int i = 0; i < 4; i++)
#pragma unroll
        for (int j = 0; j < 4; j++) acc[i][j] = floatx4{0.f, 0.f, 0.f, 0.f};

    for (int k0 = 0; k0 < DMODEL; k0 += 64) {
#pragma unroll
        for (int i = 0; i < 4; i++) {
            async16(a_src[i] + k0, &As[(i * 256 + tid) * 8]);
            async16(b_src[i] + k0, &Bs[(i * 256 + tid) * 8]);
        }
        __syncthreads();
#pragma unroll
        for (int kk = 0; kk < 2; kk++) {
            short8 af[4], bfr[4];
#pragma unroll
            for (int im = 0; im < 4; im++) {
                int m = wm + im * 16 + lm;
                int slot = (kk * 4 + quad) ^ (m & 7);
                af[im] = *(const short8*)(&As[m * 64 + slot * 8]);
            }
#pragma unroll
            for (int in = 0; in < 4; in++) {
                int n = wn + in * 16 + lm;
                int slot = (kk * 4 + quad) ^ (n & 7);
                bfr[in] = *(const short8*)(&Bs[n * 64 + slot * 8]);
            }
#pragma unroll
            for (int im = 0; im < 4; im++)
#pragma unroll
                for (int in = 0; in < 4; in++)
                    acc[im][in] = __builtin_amdgcn_mfma_f32_16x16x32_bf16(
                        af[im], bfr[in], acc[im][in], 0, 0, 0);
        }
        __syncthreads();
    }

    float b1v[4];
#pragma unroll
    for (int in = 0; in < 4; in++) b1v[in] = b1[e * DFF + nt * 128 + wn + in * 16 + lm];
#pragma unroll
    for (int im = 0; im < 4; im++) {
#pragma unroll
        for (int r = 0; r < 4; r++) {
            int row = mt * 128 + wm + im * 16 + quad * 4 + r;
            if (row < cnt) {
                size_t base = (size_t)(off + row) * DFF + nt * 128 + wn + lm;
#pragma unroll
                for (int in = 0; in < 4; in++) {
                    float v = acc[im][in][r] + b1v[in];
                    hb[base + in * 16] = f2bf(gelu_fast(v));
                }
            }
        }
    }
}

// ---------------- GEMM2: out[tok] = ew[tok]*(h @ w2 + b2) ----------------
// 512 threads / 8 waves per block: same 128x128 tile, 2x the latency-hiding
// waves per CU (grid is only ~568 blocks = 2/CU; wave count is the lever).
__global__ __launch_bounds__(512, 4) void gemm2_kernel(
    const unsigned short* __restrict__ hb,    // [T][DFF] grouped
    const unsigned short* __restrict__ w2b,   // [E][DMODEL][DFF]
    const float* __restrict__ b2,             // [E][DMODEL]
    const int* __restrict__ counts,
    const int* __restrict__ offsets,
    const int* __restrict__ perm,
    const int* __restrict__ tiletab,
    const int* __restrict__ ntiles,
    const float* __restrict__ ew,
    float* __restrict__ out)                  // [T][DMODEL]
{
    const int ti = blockIdx.y;
    if (ti >= ntiles[0]) return;
    const int tv = tiletab[ti];
    const int e = tv >> 16, mt = tv & 0xffff, nt = blockIdx.x;
    const int cnt = counts[e];
    const int off = offsets[e];
    const int tid = threadIdx.x, lane = tid & 63, wave = tid >> 6;
    const int wm = (wave >> 2) * 64, wn = (wave & 3) * 32;   // 8 waves: 2(M) x 4(N) of 64x32
    const int lm = lane & 15, quad = lane >> 4;

    __shared__ __attribute__((aligned(16))) unsigned short As[128 * 64];
    __shared__ __attribute__((aligned(16))) unsigned short Bs[128 * 64];

    const unsigned short* a_src[2];
    const unsigned short* b_src[2];
#pragma unroll
    for (int i = 0; i < 2; i++) {
        int c = i * 512 + tid;
        int row = c >> 3;
        int g = (c & 7) ^ (row & 7);
        int gr = off + mt * 128 + row;
        if (gr > T_TOK - 1) gr = T_TOK - 1;
        a_src[i] = hb + (size_t)gr * DFF + g * 8;
        b_src[i] = w2b + ((size_t)e * DMODEL + nt * 128 + row) * DFF + g * 8;
    }

    floatx4 acc[4][2];
#pragma unroll
    for (int i = 0; i < 4; i++)
#pragma unroll
        for (int j = 0; j < 2; j++) acc[i][j] = floatx4{0.f, 0.f, 0.f, 0.f};

    for (int k0 = 0; k0 < DFF; k0 += 64) {
#pragma unroll
        for (int i = 0; i < 2; i++) {
            async16(a_src[i] + k0, &As[(i * 512 + tid) * 8]);
            async16(b_src[i] + k0, &Bs[(i * 512 + tid) * 8]);
        }
        __syncthreads();
#pragma unroll
        for (int kk = 0; kk < 2; kk++) {
            short8 af[4], bfr[2];
#pragma unroll
            for (int im = 0; im < 4; im++) {
                int m = wm + im * 16 + lm;
                int slot = (kk * 4 + quad) ^ (m & 7);
                af[im] = *(const short8*)(&As[m * 64 + slot * 8]);
            }
#pragma unroll
            for (int in = 0; in < 2; in++) {
                int n = wn + in * 16 + lm;
                int slot = (kk * 4 + quad) ^ (n & 7);
                bfr[in] = *(const short8*)(&Bs[n * 64 + slot * 8]);
            }
#pragma unroll
            for (int im = 0; im < 4; im++)
#pragma unroll
                for (int in = 0; in < 2; in++)
                    acc[im][in] = __builtin_amdgcn_mfma_f32_16x16x32_bf16(
                        af[im], bfr[in], acc[im][in], 0, 0, 0);
        }
        __syncthreads();
    }

    float b2v[2];
#pragma unroll
    for (int in = 0; in < 2; in++)
        b2v[in] = b2[e * DMODEL + nt * 128 + wn + in * 16 + lm];
#pragma unroll
    for (int im = 0; im < 4; im++) {
#pragma unroll
        for (int r = 0; r < 4; r++) {
            int row = mt * 128 + wm + im * 16 + quad * 4 + r;
            if (row < cnt) {
                int tok = perm[off + row];
                float wv = ew[tok];
                size_t base = (size_t)tok * DMODEL + nt * 128 + wn + lm;
#pragma unroll
                for (int in = 0; in < 2; in++)
                    out[base + in * 16] = (acc[im][in][r] + b2v[in]) * wv;
            }
        }
    }
}

// ---------------- launch ----------------
extern "C" void kernel_launch(void* const* d_in, const int* in_sizes, int n_in,
                              void* d_out, int out_size, void* d_ws, size_t ws_size,
                              hipStream_t stream) {
    const float* x      = (const float*)d_in[0];
    const float* gate_w = (const float*)d_in[1];
    const float* w1     = (const float*)d_in[2];
    const float* b1     = (const float*)d_in[3];
    const float* w2     = (const float*)d_in[4];
    const float* b2     = (const float*)d_in[5];
    float* out = (float*)d_out;
    char* ws = (char*)d_ws;

    int* counts  = (int*)(ws + OFF_COUNTS);
    int* cursor  = (int*)(ws + OFF_CURSOR);
    int* offsets = (int*)(ws + OFF_OFFSETS);
    int* tiletab = (int*)(ws + OFF_TILES);
    int* ntiles  = (int*)(ws + OFF_NTILES);
    int* eidx    = (int*)(ws + OFF_EIDX);
    float* ew    = (float*)(ws + OFF_EW);
    int* perm    = (int*)(ws + OFF_PERM);
    unsigned short* xb  = (unsigned short*)(ws + OFF_XB);
    unsigned short* w1b = (unsigned short*)(ws + OFF_W1B);
    unsigned short* w2b = (unsigned short*)(ws + OFF_W2B);
    unsigned short* hb  = (unsigned short*)(ws + OFF_HB);

    zero_kernel<<<1, 64, 0, stream>>>(counts, cursor);
    {
        dim3 g(DMODEL / 64, DFF / 64, NEXP);   // w1: K=DMODEL, N=DFF
        transpose_cvt_kernel<<<g, 256, 0, stream>>>(w1, w1b, DMODEL, DFF);
    }
    {
        dim3 g(DFF / 64, DMODEL / 64, NEXP);   // w2: K=DFF, N=DMODEL
        transpose_cvt_kernel<<<g, 256, 0, stream>>>(w2, w2b, DFF, DMODEL);
    }
    router_kernel<<<T_TOK / 4, 256, 0, stream>>>(x, gate_w, eidx, ew, xb, counts);
    scan_kernel<<<1, 64, 0, stream>>>(counts, offsets, cursor, tiletab, ntiles);
    scatter_kernel<<<T_TOK / 256, 256, 0, stream>>>(eidx, cursor, perm);
    {
        dim3 g(DFF / 128, MAXTILES);
        gemm1_kernel<<<g, 256, 0, stream>>>(xb, w1b, b1, counts, offsets, perm,
                                            tiletab, ntiles, hb);
    }
    {
        dim3 g(DMODEL / 128, MAXTILES);
        gemm2_kernel<<<g, 512, 0, stream>>>(hb, w2b, b2, counts, offsets, perm,
                                            tiletab, ntiles, ew, out);
    }
}

// Round 5
// 570.259 us; speedup vs baseline: 1.0822x; 1.0822x over previous
//
#include <hip/hip_runtime.h>
#include <math.h>
#include <stdint.h>

// ---------------- problem constants ----------------
#define T_TOK  8192
#define DMODEL 1024
#define DFF    4096
#define NEXP   8
#define MAXTILES 71      // sum ceil(cnt_e/128) <= 64 + (NEXP-1)

// ---------------- workspace layout (bytes) ----------------
static constexpr size_t OFF_COUNTS  = 0;
static constexpr size_t OFF_CURSOR  = 64;
static constexpr size_t OFF_OFFSETS = 128;
static constexpr size_t OFF_TILES   = 256;   // MAXTILES ints
static constexpr size_t OFF_NTILES  = 768;
static constexpr size_t OFF_EIDX    = 1024;
static constexpr size_t OFF_EW      = OFF_EIDX + (size_t)T_TOK * 4;
static constexpr size_t OFF_PERM    = OFF_EW   + (size_t)T_TOK * 4;
static constexpr size_t OFF_XB      = 131072;                                   // bf16 x  [T][D]
static constexpr size_t OFF_W1B     = OFF_XB  + (size_t)T_TOK * DMODEL * 2;     // bf16 w1^T [E][DFF][D]
static constexpr size_t OFF_W2B     = OFF_W1B + (size_t)NEXP * DFF * DMODEL * 2;// bf16 w2^T [E][D][DFF]
static constexpr size_t OFF_HB      = OFF_W2B + (size_t)NEXP * DMODEL * DFF * 2;// bf16 h  [T][DFF] grouped

typedef __attribute__((ext_vector_type(8))) short short8;
typedef __attribute__((ext_vector_type(4))) float floatx4;

__device__ __forceinline__ unsigned short f2bf(float f) {
    unsigned u = __builtin_bit_cast(unsigned, f);
    u += 0x7fffu + ((u >> 16) & 1u);   // round-to-nearest-even
    return (unsigned short)(u >> 16);
}

__device__ __forceinline__ void async16(const unsigned short* g, unsigned short* l) {
    __builtin_amdgcn_global_load_lds(
        (const __attribute__((address_space(1))) unsigned*)g,
        (__attribute__((address_space(3))) unsigned*)l, 16, 0, 0);
}

// tanh-form GELU via sigmoid: gelu(x) ~= x * sigmoid(2*sqrt(2/pi)*(x+0.044715x^3))
// max abs error vs exact-erf GELU ~3e-4, far below bf16 quantization of h.
__device__ __forceinline__ float gelu_fast(float v) {
    float u2 = v * (1.5957691216f + 0.0713548163f * v * v);
    return v / (1.0f + __expf(-u2));
}

// ---------------- small setup kernels ----------------
__global__ void zero_kernel(int* counts, int* cursor) {
    int t = threadIdx.x;
    if (t < NEXP) { counts[t] = 0; cursor[t] = 0; }
}

// src [E][K][N] fp32  ->  dst [E][N][K] bf16, 16B vectorized both sides
__global__ __launch_bounds__(256) void transpose_cvt_kernel(const float* __restrict__ src,
                                                            unsigned short* __restrict__ dst,
                                                            int K, int N) {
    int e  = blockIdx.z;
    int k0 = blockIdx.x * 64;
    int n0 = blockIdx.y * 64;
    const float* s = src + (size_t)e * K * N;
    unsigned short* d = dst + (size_t)e * K * N;
    __shared__ float tile[64][65];
    int tid = threadIdx.x;
    int lane16 = tid & 15, rowb = tid >> 4;   // 16 rows per pass
#pragma unroll
    for (int i = 0; i < 4; i++) {
        int row = i * 16 + rowb;
        float4 v = *(const float4*)(s + (size_t)(k0 + row) * N + n0 + lane16 * 4);
        tile[row][lane16 * 4 + 0] = v.x;
        tile[row][lane16 * 4 + 1] = v.y;
        tile[row][lane16 * 4 + 2] = v.z;
        tile[row][lane16 * 4 + 3] = v.w;
    }
    __syncthreads();
    int n = tid >> 2, kq = tid & 3;
#pragma unroll
    for (int h = 0; h < 2; h++) {
        int kk = (kq + h * 4) * 8;
        unsigned pk[4];
#pragma unroll
        for (int j = 0; j < 4; j++) {
            unsigned lo = f2bf(tile[kk + 2 * j][n]);
            unsigned hi = f2bf(tile[kk + 2 * j + 1][n]);
            pk[j] = lo | (hi << 16);
        }
        *(uint4*)(d + (size_t)(n0 + n) * K + k0 + kk) = *(uint4*)pk;
    }
}

// ---------------- router: logits via LDS-transposed gate_w, softmax, argmax,
// fused per-block expert histogram; also emits xb (bf16 x) ----------------
__global__ __launch_bounds__(256) void router_kernel(const float* __restrict__ x,
                                                     const float* __restrict__ gw,
                                                     int* __restrict__ eidx,
                                                     float* __restrict__ ew,
                                                     unsigned short* __restrict__ xb,
                                                     int* __restrict__ counts) {
    __shared__ float gwT[NEXP][DMODEL];   // 32 KiB, transposed gate_w
    __shared__ int lh[NEXP];
    int tid = threadIdx.x, lane = tid & 63, w = tid >> 6;
    if (tid < NEXP) lh[tid] = 0;
    {   // cooperative load gw [1024][8] -> gwT[e][d]; 4 d-rows per thread
        int d0 = tid * 4;
        const float* g = gw + (size_t)d0 * NEXP;
        float4 a0 = *(const float4*)(g +  0), b0 = *(const float4*)(g +  4);
        float4 a1 = *(const float4*)(g +  8), b1 = *(const float4*)(g + 12);
        float4 a2 = *(const float4*)(g + 16), b2 = *(const float4*)(g + 20);
        float4 a3 = *(const float4*)(g + 24), b3 = *(const float4*)(g + 28);
        *(float4*)&gwT[0][d0] = float4{a0.x, a1.x, a2.x, a3.x};
        *(float4*)&gwT[1][d0] = float4{a0.y, a1.y, a2.y, a3.y};
        *(float4*)&gwT[2][d0] = float4{a0.z, a1.z, a2.z, a3.z};
        *(float4*)&gwT[3][d0] = float4{a0.w, a1.w, a2.w, a3.w};
        *(float4*)&gwT[4][d0] = float4{b0.x, b1.x, b2.x, b3.x};
        *(float4*)&gwT[5][d0] = float4{b0.y, b1.y, b2.y, b3.y};
        *(float4*)&gwT[6][d0] = float4{b0.z, b1.z, b2.z, b3.z};
        *(float4*)&gwT[7][d0] = float4{b0.w, b1.w, b2.w, b3.w};
    }
    __syncthreads();

    int t = blockIdx.x * 4 + w;
    float acc[NEXP];
#pragma unroll
    for (int e = 0; e < NEXP; e++) acc[e] = 0.f;
    const float* xr = x + (size_t)t * DMODEL;
    unsigned short* xbr = xb + (size_t)t * DMODEL;
#pragma unroll
    for (int i = 0; i < 4; i++) {
        int dbase = i * 256 + lane * 4;
        float4 xv = *(const float4*)(xr + dbase);
        uint2 p;
        p.x = (unsigned)f2bf(xv.x) | ((unsigned)f2bf(xv.y) << 16);
        p.y = (unsigned)f2bf(xv.z) | ((unsigned)f2bf(xv.w) << 16);
        *(uint2*)(xbr + dbase) = p;
#pragma unroll
        for (int e = 0; e < NEXP; e++) {
            float4 g = *(const float4*)&gwT[e][dbase];   // ds_read_b128, conflict-free
            acc[e] += xv.x * g.x + xv.y * g.y + xv.z * g.z + xv.w * g.w;
        }
    }
#pragma unroll
    for (int e = 0; e < NEXP; e++) {
#pragma unroll
        for (int o = 32; o > 0; o >>= 1) acc[e] += __shfl_xor(acc[e], o, 64);
    }
    float m = acc[0]; int a = 0;
#pragma unroll
    for (int e = 1; e < NEXP; e++) { if (acc[e] > m) { m = acc[e]; a = e; } }
    float s = 0.f;
#pragma unroll
    for (int e = 0; e < NEXP; e++) s += expf(acc[e] - m);
    if (lane == 0) { eidx[t] = a; ew[t] = 1.0f / s; atomicAdd(&lh[a], 1); }
    __syncthreads();
    if (tid < NEXP && lh[tid]) atomicAdd(&counts[tid], lh[tid]);
}

// ---------------- grouping ----------------
__global__ void scan_kernel(const int* __restrict__ counts, int* __restrict__ offsets,
                            int* __restrict__ cursor, int* __restrict__ tiletab,
                            int* __restrict__ ntiles) {
    if (threadIdx.x == 0) {
        int s = 0, nt = 0;
        for (int e = 0; e < NEXP; e++) {
            offsets[e] = s; cursor[e] = s;
            int c = counts[e];
            int m = (c + 127) >> 7;
            for (int i = 0; i < m; i++) tiletab[nt++] = (e << 16) | i;
            s += c;
        }
        offsets[NEXP] = s;
        ntiles[0] = nt;
    }
}

__global__ void scatter_kernel(const int* __restrict__ eidx, int* __restrict__ cursor,
                               int* __restrict__ perm) {
    __shared__ int lh[NEXP];
    __shared__ int lbase[NEXP];
    int tid = threadIdx.x;
    if (tid < NEXP) lh[tid] = 0;
    __syncthreads();
    int t = blockIdx.x * 256 + tid;
    int e = eidx[t];
    int lpos = atomicAdd(&lh[e], 1);
    __syncthreads();
    if (tid < NEXP) lbase[tid] = atomicAdd(&cursor[tid], lh[tid]);
    __syncthreads();
    perm[lbase[e] + lpos] = t;
}

// ---------------- GEMM1: h = gelu(x[perm] @ w1 + b1), bf16 MFMA ----------------
// __launch_bounds__(256,2): 2 resident blocks/CU is the cache-friendly point —
// (256,4) raised occupancy to 37% but blew FETCH 107->184MB / WRITE 65->111MB
// (L2 thrash + partial-line write amplification) and cost +40us. Do not raise.
__global__ __launch_bounds__(256, 2) void gemm1_kernel(
    const unsigned short* __restrict__ xb,
    const unsigned short* __restrict__ w1b,   // [E][DFF][DMODEL]
    const float* __restrict__ b1,             // [E][DFF]
    const int* __restrict__ counts,
    const int* __restrict__ offsets,
    const int* __restrict__ perm,
    const int* __restrict__ tiletab,
    const int* __restrict__ ntiles,
    unsigned short* __restrict__ hb)          // [T][DFF] grouped rows
{
    const int ti = blockIdx.y;
    if (ti >= ntiles[0]) return;
    const int tv = tiletab[ti];
    const int e = tv >> 16, mt = tv & 0xffff, nt = blockIdx.x;
    const int cnt = counts[e];
    const int off = offsets[e];
    const int tid = threadIdx.x, lane = tid & 63, wave = tid >> 6;
    const int wm = (wave >> 1) * 64, wn = (wave & 1) * 64;
    const int lm = lane & 15, quad = lane >> 4;

    __shared__ __attribute__((aligned(16))) unsigned short As[128 * 64];
    __shared__ __attribute__((aligned(16))) unsigned short Bs[128 * 64];

    const unsigned short* a_src[4];
    const unsigned short* b_src[4];
    const int cntLoc = cnt - mt * 128;
#pragma unroll
    for (int i = 0; i < 4; i++) {
        int c = i * 256 + tid;
        int row = c >> 3;
        int g = (c & 7) ^ (row & 7);          // XOR-swizzled 16B granule
        int r = (row < cntLoc) ? row : 0;
        int tok = perm[off + mt * 128 + r];
        a_src[i] = xb + (size_t)tok * DMODEL + g * 8;
        b_src[i] = w1b + ((size_t)e * DFF + nt * 128 + row) * DMODEL + g * 8;
    }

    floatx4 acc[4][4];
#pragma unroll
    for (int i = 0; i < 4; i++)
#pragma unroll
        for (int j = 0; j < 4; j++) acc[i][j] = floatx4{0.f, 0.f, 0.f, 0.f};

    for (int k0 = 0; k0 < DMODEL; k0 += 64) {
#pragma unroll
        for (int i = 0; i < 4; i++) {
            async16(a_src[i] + k0, &As[(i * 256 + tid) * 8]);
            async16(b_src[i] + k0, &Bs[(i * 256 + tid) * 8]);
        }
        __syncthreads();
#pragma unroll
        for (int kk = 0; kk < 2; kk++) {
            short8 af[4], bfr[4];
#pragma unroll
            for (int im = 0; im < 4; im++) {
                int m = wm + im * 16 + lm;
                int slot = (kk * 4 + quad) ^ (m & 7);
                af[im] = *(const short8*)(&As[m * 64 + slot * 8]);
            }
#pragma unroll
            for (int in = 0; in < 4; in++) {
                int n = wn + in * 16 + lm;
                int slot = (kk * 4 + quad) ^ (n & 7);
                bfr[in] = *(const short8*)(&Bs[n * 64 + slot * 8]);
            }
#pragma unroll
            for (int im = 0; im < 4; im++)
#pragma unroll
                for (int in = 0; in < 4; in++)
                    acc[im][in] = __builtin_amdgcn_mfma_f32_16x16x32_bf16(
                        af[im], bfr[in], acc[im][in], 0, 0, 0);
        }
        __syncthreads();
    }

    float b1v[4];
#pragma unroll
    for (int in = 0; in < 4; in++) b1v[in] = b1[e * DFF + nt * 128 + wn + in * 16 + lm];
#pragma unroll
    for (int im = 0; im < 4; im++) {
#pragma unroll
        for (int r = 0; r < 4; r++) {
            int row = mt * 128 + wm + im * 16 + quad * 4 + r;
            if (row < cnt) {
                size_t base = (size_t)(off + row) * DFF + nt * 128 + wn + lm;
#pragma unroll
                for (int in = 0; in < 4; in++) {
                    float v = acc[im][in][r] + b1v[in];
                    hb[base + in * 16] = f2bf(gelu_fast(v));
                }
            }
        }
    }
}

// ---------------- GEMM2: out[tok] = ew[tok]*(h @ w2 + b2) ----------------
// 512 threads / 8 waves per block: same 128x128 tile, 2x the latency-hiding
// waves per CU (grid is only ~568 blocks = 2/CU; wave count is the lever).
__global__ __launch_bounds__(512, 4) void gemm2_kernel(
    const unsigned short* __restrict__ hb,    // [T][DFF] grouped
    const unsigned short* __restrict__ w2b,   // [E][DMODEL][DFF]
    const float* __restrict__ b2,             // [E][DMODEL]
    const int* __restrict__ counts,
    const int* __restrict__ offsets,
    const int* __restrict__ perm,
    const int* __restrict__ tiletab,
    const int* __restrict__ ntiles,
    const float* __restrict__ ew,
    float* __restrict__ out)                  // [T][DMODEL]
{
    const int ti = blockIdx.y;
    if (ti >= ntiles[0]) return;
    const int tv = tiletab[ti];
    const int e = tv >> 16, mt = tv & 0xffff, nt = blockIdx.x;
    const int cnt = counts[e];
    const int off = offsets[e];
    const int tid = threadIdx.x, lane = tid & 63, wave = tid >> 6;
    const int wm = (wave >> 2) * 64, wn = (wave & 3) * 32;   // 8 waves: 2(M) x 4(N) of 64x32
    const int lm = lane & 15, quad = lane >> 4;

    __shared__ __attribute__((aligned(16))) unsigned short As[128 * 64];
    __shared__ __attribute__((aligned(16))) unsigned short Bs[128 * 64];

    const unsigned short* a_src[2];
    const unsigned short* b_src[2];
#pragma unroll
    for (int i = 0; i < 2; i++) {
        int c = i * 512 + tid;
        int row = c >> 3;
        int g = (c & 7) ^ (row & 7);
        int gr = off + mt * 128 + row;
        if (gr > T_TOK - 1) gr = T_TOK - 1;
        a_src[i] = hb + (size_t)gr * DFF + g * 8;
        b_src[i] = w2b + ((size_t)e * DMODEL + nt * 128 + row) * DFF + g * 8;
    }

    floatx4 acc[4][2];
#pragma unroll
    for (int i = 0; i < 4; i++)
#pragma unroll
        for (int j = 0; j < 2; j++) acc[i][j] = floatx4{0.f, 0.f, 0.f, 0.f};

    for (int k0 = 0; k0 < DFF; k0 += 64) {
#pragma unroll
        for (int i = 0; i < 2; i++) {
            async16(a_src[i] + k0, &As[(i * 512 + tid) * 8]);
            async16(b_src[i] + k0, &Bs[(i * 512 + tid) * 8]);
        }
        __syncthreads();
#pragma unroll
        for (int kk = 0; kk < 2; kk++) {
            short8 af[4], bfr[2];
#pragma unroll
            for (int im = 0; im < 4; im++) {
                int m = wm + im * 16 + lm;
                int slot = (kk * 4 + quad) ^ (m & 7);
                af[im] = *(const short8*)(&As[m * 64 + slot * 8]);
            }
#pragma unroll
            for (int in = 0; in < 2; in++) {
                int n = wn + in * 16 + lm;
                int slot = (kk * 4 + quad) ^ (n & 7);
                bfr[in] = *(const short8*)(&Bs[n * 64 + slot * 8]);
            }
#pragma unroll
            for (int im = 0; im < 4; im++)
#pragma unroll
                for (int in = 0; in < 2; in++)
                    acc[im][in] = __builtin_amdgcn_mfma_f32_16x16x32_bf16(
                        af[im], bfr[in], acc[im][in], 0, 0, 0);
        }
        __syncthreads();
    }

    float b2v[2];
#pragma unroll
    for (int in = 0; in < 2; in++)
        b2v[in] = b2[e * DMODEL + nt * 128 + wn + in * 16 + lm];
#pragma unroll
    for (int im = 0; im < 4; im++) {
#pragma unroll
        for (int r = 0; r < 4; r++) {
            int row = mt * 128 + wm + im * 16 + quad * 4 + r;
            if (row < cnt) {
                int tok = perm[off + row];
                float wv = ew[tok];
                size_t base = (size_t)tok * DMODEL + nt * 128 + wn + lm;
#pragma unroll
                for (int in = 0; in < 2; in++)
                    out[base + in * 16] = (acc[im][in][r] + b2v[in]) * wv;
            }
        }
    }
}

// ---------------- launch ----------------
extern "C" void kernel_launch(void* const* d_in, const int* in_sizes, int n_in,
                              void* d_out, int out_size, void* d_ws, size_t ws_size,
                              hipStream_t stream) {
    const float* x      = (const float*)d_in[0];
    const float* gate_w = (const float*)d_in[1];
    const float* w1     = (const float*)d_in[2];
    const float* b1     = (const float*)d_in[3];
    const float* w2     = (const float*)d_in[4];
    const float* b2     = (const float*)d_in[5];
    float* out = (float*)d_out;
    char* ws = (char*)d_ws;

    int* counts  = (int*)(ws + OFF_COUNTS);
    int* cursor  = (int*)(ws + OFF_CURSOR);
    int* offsets = (int*)(ws + OFF_OFFSETS);
    int* tiletab = (int*)(ws + OFF_TILES);
    int* ntiles  = (int*)(ws + OFF_NTILES);
    int* eidx    = (int*)(ws + OFF_EIDX);
    float* ew    = (float*)(ws + OFF_EW);
    int* perm    = (int*)(ws + OFF_PERM);
    unsigned short* xb  = (unsigned short*)(ws + OFF_XB);
    unsigned short* w1b = (unsigned short*)(ws + OFF_W1B);
    unsigned short* w2b = (unsigned short*)(ws + OFF_W2B);
    unsigned short* hb  = (unsigned short*)(ws + OFF_HB);

    zero_kernel<<<1, 64, 0, stream>>>(counts, cursor);
    {
        dim3 g(DMODEL / 64, DFF / 64, NEXP);   // w1: K=DMODEL, N=DFF
        transpose_cvt_kernel<<<g, 256, 0, stream>>>(w1, w1b, DMODEL, DFF);
    }
    {
        dim3 g(DFF / 64, DMODEL / 64, NEXP);   // w2: K=DFF, N=DMODEL
        transpose_cvt_kernel<<<g, 256, 0, stream>>>(w2, w2b, DFF, DMODEL);
    }
    router_kernel<<<T_TOK / 4, 256, 0, stream>>>(x, gate_w, eidx, ew, xb, counts);
    scan_kernel<<<1, 64, 0, stream>>>(counts, offsets, cursor, tiletab, ntiles);
    scatter_kernel<<<T_TOK / 256, 256, 0, stream>>>(eidx, cursor, perm);
    {
        dim3 g(DFF / 128, MAXTILES);
        gemm1_kernel<<<g, 256, 0, stream>>>(xb, w1b, b1, counts, offsets, perm,
                                            tiletab, ntiles, hb);
    }
    {
        dim3 g(DMODEL / 128, MAXTILES);
        gemm2_kernel<<<g, 512, 0, stream>>>(hb, w2b, b2, counts, offsets, perm,
                                            tiletab, ntiles, ew, out);
    }
}